// Round 10
// baseline (199.070 us; speedup 1.0000x reference)
//
#include <hip/hip_runtime.h>

#define C_DIM 512
#define N_PIX 2304   // 48*48
#define B_DIM 16
#define K8    (C_DIM / 8)          // 64 groups of 8 k
#define K8_STRIDE (N_PIX * 8)      // ushorts per k8 row  (18432)
#define FB_STRIDE ((size_t)K8 * K8_STRIDE)  // ushorts per batch (1179648)
#define NB (B_DIM * N_PIX)         // 36864 pixels total

typedef float floatx4 __attribute__((ext_vector_type(4)));
typedef __bf16 bf16x8 __attribute__((ext_vector_type(8)));

// fp32 -> bf16 round-to-nearest-even
static __device__ __forceinline__ unsigned short f2bf(float f) {
    unsigned u = __float_as_uint(f);
    return (unsigned short)((u + 0x7fffu + ((u >> 16) & 1u)) >> 16);
}

static __device__ __forceinline__ float softplus_stable(float z) {
    return (z > 0.f) ? (z + log1pf(expf(-z))) : log1pf(expf(z));
}

// ---------------------------------------------------------------------------
// Kernel 1 (xcvt): single pass over x (R6-bench proven form).
// Grid (144, 16): block = 256 pixels x 32 channels (4 k8 groups).
//   - F[b][k/8][n][k%8] = bf16(raw x)
//   - accd[b,n] += partial dot(w,x); accs[b,n] += partial sum x^2 (atomics)
// ---------------------------------------------------------------------------
__global__ __launch_bounds__(256) void xcvt_kernel(const float* __restrict__ x,
                                                   const float* __restrict__ w,
                                                   unsigned short* __restrict__ F,
                                                   float* __restrict__ accd,
                                                   float* __restrict__ accs) {
    const int pg = blockIdx.x;                 // 0..143 pixel group
    const int cg = blockIdx.y;                 // 0..15 channel group
    const int b  = pg / 9;
    const int p  = (pg - b * 9) * 256 + threadIdx.x;   // pixel within batch
    const float* xb = x + (size_t)b * C_DIM * N_PIX + p;

    float dot = 0.f, sq = 0.f;
    #pragma unroll
    for (int k8l = 0; k8l < 4; ++k8l) {
        const int k8 = cg * 4 + k8l;
        float v[8];
        #pragma unroll
        for (int kk = 0; kk < 8; ++kk)
            v[kk] = xb[(size_t)(k8 * 8 + kk) * N_PIX];
        union { unsigned short u[8]; int4 q; } cell;
        #pragma unroll
        for (int kk = 0; kk < 8; ++kk) {
            dot = fmaf(v[kk], w[k8 * 8 + kk], dot);
            sq  = fmaf(v[kk], v[kk], sq);
            cell.u[kk] = f2bf(v[kk]);
        }
        *(int4*)(F + (size_t)b * FB_STRIDE + (size_t)k8 * K8_STRIDE + (size_t)p * 8) = cell.q;
    }
    atomicAdd(&accd[b * N_PIX + p], dot);
    atomicAdd(&accs[b * N_PIX + p], sq);
}

// ---------------------------------------------------------------------------
// Kernel 1b (finalize): g = softplus(dot)*rn2, rn2 = 1/max(sq,eps), refine=0.
// ---------------------------------------------------------------------------
__global__ __launch_bounds__(256) void finalize_kernel(const float* __restrict__ accd,
                                                       const float* __restrict__ accs,
                                                       float* __restrict__ g,
                                                       float* __restrict__ rn2,
                                                       float* __restrict__ refine) {
    const int bp = blockIdx.x * 256 + threadIdx.x;
    const float d = accd[bp];
    const float s = accs[bp];
    const float r2 = 1.0f / fmaxf(s, 1e-24f);
    g[bp]      = softplus_stable(d) * r2;
    rn2[bp]    = r2;
    refine[bp] = 0.f;
}

// ---------------------------------------------------------------------------
// Kernel 2: symmetric-triangle refine, XCD-partitioned, NO LDS / NO BARRIERS.
// Each lane's MFMA fragment is 16 contiguous bytes of F (fragment-layout
// precomputed by xcvt), so fragments load straight from L2 into registers
// (global_load_dwordx4), software-pipelined one chunk ahead. Waves slip
// independently; compiler emits fine-grained per-register vmcnt waits —
// the AITER-style interleave the barriered LDS loop couldn't express
// (R9 dbuf/R5 BK=64 both regressed; this removes the structure, not tweaks).
// ---------------------------------------------------------------------------
__global__ __launch_bounds__(256) void refine_kernel(const unsigned short* __restrict__ F,
                                                     const float* __restrict__ g,
                                                     float* __restrict__ refine) {
    // decode: XCD-partitioned (id%8 ~ XCD), then triangular tile
    const int id   = blockIdx.x;
    const int xcd  = id & 7;
    const int slot = id >> 3;                  // 0..341
    const int hi   = (slot >= 171) ? 1 : 0;
    const int b    = xcd + 8 * hi;
    int t = slot - 171 * hi, bi = 0;
    while (t >= 18 - bi) { t -= 18 - bi; ++bi; }
    const int bj = bi + t;
    const int n0 = bi * 128;          // rows
    const int m0 = bj * 128;          // cols
    const bool mirror = (bi != bj);

    const unsigned short* Fb = F + (size_t)b * FB_STRIDE;
    const float* gb = g + b * N_PIX;

    const int tid  = threadIdx.x;
    const int lane = tid & 63;
    const int wave = tid >> 6;
    const int wr = wave >> 1, wc = wave & 1;
    const int quad = lane >> 4, lcol = lane & 15;

    floatx4 acc[4][4];
    #pragma unroll
    for (int i = 0; i < 4; ++i)
        #pragma unroll
        for (int j = 0; j < 4; ++j)
            acc[i][j] = (floatx4)0.f;

    // per-lane fragment base pointers (chunk 0, frag mi/ni = +mi*128 ushorts)
    const size_t cstride = (size_t)4 * K8_STRIDE;          // ushorts per K-chunk
    const unsigned short* pA = Fb + (size_t)quad * K8_STRIDE + (size_t)(n0 + wr * 64 + lcol) * 8;
    const unsigned short* pB = Fb + (size_t)quad * K8_STRIDE + (size_t)(m0 + wc * 64 + lcol) * 8;

    bf16x8 ca[4], cb[4];
    #pragma unroll
    for (int i = 0; i < 4; ++i) {
        ca[i] = *(const bf16x8*)(pA + i * 128);
        cb[i] = *(const bf16x8*)(pB + i * 128);
    }

    #pragma unroll
    for (int ck = 0; ck < 15; ++ck) {
        // prefetch chunk ck+1 into fresh registers (independent of MFMAs below)
        const unsigned short* qA = pA + (size_t)(ck + 1) * cstride;
        const unsigned short* qB = pB + (size_t)(ck + 1) * cstride;
        bf16x8 na[4], nb[4];
        #pragma unroll
        for (int i = 0; i < 4; ++i) {
            na[i] = *(const bf16x8*)(qA + i * 128);
            nb[i] = *(const bf16x8*)(qB + i * 128);
        }
        // 16 MFMAs on current chunk (overlaps the in-flight prefetch)
        #pragma unroll
        for (int mi = 0; mi < 4; ++mi)
            #pragma unroll
            for (int ni = 0; ni < 4; ++ni)
                acc[mi][ni] = __builtin_amdgcn_mfma_f32_16x16x32_bf16(ca[mi], cb[ni], acc[mi][ni], 0, 0, 0);
        #pragma unroll
        for (int i = 0; i < 4; ++i) { ca[i] = na[i]; cb[i] = nb[i]; }
    }
    #pragma unroll
    for (int mi = 0; mi < 4; ++mi)
        #pragma unroll
        for (int ni = 0; ni < 4; ++ni)
            acc[mi][ni] = __builtin_amdgcn_mfma_f32_16x16x32_bf16(ca[mi], cb[ni], acc[mi][ni], 0, 0, 0);

    // ---- standard contribution: reduce over cols -> refine_raw[rows]
    float gC[4];
    #pragma unroll
    for (int ni = 0; ni < 4; ++ni)
        gC[ni] = gb[m0 + wc * 64 + ni * 16 + lcol];

    #pragma unroll
    for (int mi = 0; mi < 4; ++mi) {
        float part[4] = {0.f, 0.f, 0.f, 0.f};
        #pragma unroll
        for (int ni = 0; ni < 4; ++ni) {
            #pragma unroll
            for (int r = 0; r < 4; ++r) {
                float s = fmaxf(acc[mi][ni][r], 0.f);
                part[r] = fmaf(s * s, gC[ni], part[r]);
            }
        }
        #pragma unroll
        for (int r = 0; r < 4; ++r) {
            float v = part[r];
            v += __shfl_xor(v, 1);
            v += __shfl_xor(v, 2);
            v += __shfl_xor(v, 4);
            v += __shfl_xor(v, 8);
            if (lcol == 0)
                atomicAdd(&refine[b * N_PIX + n0 + wr * 64 + mi * 16 + quad * 4 + r], v);
        }
    }

    // ---- mirror contribution: reduce over rows -> refine_raw[cols]
    if (mirror) {
        float gR[4][4];
        #pragma unroll
        for (int mi = 0; mi < 4; ++mi)
            #pragma unroll
            for (int r = 0; r < 4; ++r)
                gR[mi][r] = gb[n0 + wr * 64 + mi * 16 + quad * 4 + r];

        #pragma unroll
        for (int ni = 0; ni < 4; ++ni) {
            float msum = 0.f;
            #pragma unroll
            for (int mi = 0; mi < 4; ++mi) {
                #pragma unroll
                for (int r = 0; r < 4; ++r) {
                    float s = fmaxf(acc[mi][ni][r], 0.f);
                    msum = fmaf(s * s, gR[mi][r], msum);
                }
            }
            msum += __shfl_xor(msum, 16);
            msum += __shfl_xor(msum, 32);
            if (quad == 0)
                atomicAdd(&refine[b * N_PIX + m0 + wc * 64 + ni * 16 + lcol], msum);
        }
    }
}

// ---------------------------------------------------------------------------
// Kernel 3 (pool): out[b,c] = mean_n F[b,c,n] * refine_raw[n] * rn2[n]
// One block per (b,k8): grid 1024, 4 waves split the 36 n-strips.
// ---------------------------------------------------------------------------
__global__ __launch_bounds__(256) void pool_kernel(const unsigned short* __restrict__ F,
                                                   const float* __restrict__ refine,
                                                   const float* __restrict__ rn2,
                                                   float* __restrict__ out) {
    const int lane = threadIdx.x & 63;
    const int wave = threadIdx.x >> 6;
    const int b  = blockIdx.x >> 6;
    const int k8 = blockIdx.x & 63;
    const unsigned short* Fr = F + (size_t)b * FB_STRIDE + (size_t)k8 * K8_STRIDE;
    const float* rf = refine + b * N_PIX;
    const float* r2 = rn2 + b * N_PIX;
    float s[8] = {0.f, 0.f, 0.f, 0.f, 0.f, 0.f, 0.f, 0.f};
    #pragma unroll
    for (int j = 0; j < 9; ++j) {             // (j*4+wave) in 0..35
        const int n = (j * 4 + wave) * 64 + lane;
        bf16x8 fv = *(const bf16x8*)(Fr + (size_t)n * 8);
        float rr = rf[n] * r2[n];
        #pragma unroll
        for (int kk = 0; kk < 8; ++kk)
            s[kk] = fmaf((float)fv[kk], rr, s[kk]);
    }
    __shared__ float sred[4][8];
    #pragma unroll
    for (int kk = 0; kk < 8; ++kk) {
        float v = s[kk];
        #pragma unroll
        for (int off = 32; off > 0; off >>= 1) v += __shfl_down(v, off);
        if (lane == 0) sred[wave][kk] = v;
    }
    __syncthreads();
    if (threadIdx.x < 8) {
        const int kk = threadIdx.x;
        out[b * C_DIM + k8 * 8 + kk] =
            (sred[0][kk] + sred[1][kk] + sred[2][kk] + sred[3][kk]) * (1.0f / N_PIX);
    }
}

// ---------------------------------------------------------------------------
// Fallback path (ws too small): R1-style, no F materialization.
// ---------------------------------------------------------------------------
__global__ __launch_bounds__(256) void prep_kernel(const float* __restrict__ x,
                                                   const float* __restrict__ w,
                                                   float* __restrict__ rnorm,
                                                   float* __restrict__ att) {
    const int tid = threadIdx.x;
    const int px = tid & 63;
    const int cc = tid >> 6;
    const int pglob = blockIdx.x * 64 + px;
    const int b = pglob / N_PIX;
    const int p = pglob - b * N_PIX;

    const float* xb = x + (size_t)b * C_DIM * N_PIX + p;
    float dot = 0.f, sq = 0.f;
    #pragma unroll 4
    for (int c = cc * 128; c < cc * 128 + 128; ++c) {
        float v = xb[(size_t)c * N_PIX];
        dot = fmaf(v, w[c], dot);
        sq  = fmaf(v, v, sq);
    }
    __shared__ float sdot[4][64];
    __shared__ float ssq[4][64];
    sdot[cc][px] = dot;
    ssq[cc][px]  = sq;
    __syncthreads();
    if (cc == 0) {
        dot = sdot[0][px] + sdot[1][px] + sdot[2][px] + sdot[3][px];
        sq  = ssq[0][px]  + ssq[1][px]  + ssq[2][px]  + ssq[3][px];
        att[pglob] = softplus_stable(dot);
        rnorm[pglob] = 1.0f / fmaxf(sqrtf(sq), 1e-12f);
    }
}

__global__ __launch_bounds__(256) void refine_fallback(const float* __restrict__ x,
                                                       const float* __restrict__ rnorm,
                                                       const float* __restrict__ att,
                                                       float* __restrict__ refine) {
    const int b  = blockIdx.z;
    const int n0 = blockIdx.x * 128;
    const int m0 = blockIdx.y * 128;
    const float* xb = x + (size_t)b * C_DIM * N_PIX;
    const float* rn = rnorm + b * N_PIX;
    const float* ab = att + b * N_PIX;

    __shared__ __align__(16) unsigned short As[4 * 128 * 8];
    __shared__ __align__(16) unsigned short Bs[4 * 128 * 8];

    const int tid  = threadIdx.x;
    const int nl   = tid & 127;
    const int half = tid >> 7;
    const int lane = tid & 63;
    const int wave = tid >> 6;
    const int wr = wave >> 1, wc = wave & 1;
    const int quad = lane >> 4, lcol = lane & 15;

    const float rA = rn[n0 + nl];
    const float rB = rn[m0 + nl];

    floatx4 acc[4][4];
    #pragma unroll
    for (int i = 0; i < 4; ++i)
        #pragma unroll
        for (int j = 0; j < 4; ++j)
            acc[i][j] = (floatx4)0.f;

    for (int k0 = 0; k0 < C_DIM; k0 += 32) {
        const float* xa = xb + (size_t)(k0 + half * 16) * N_PIX;
        union { unsigned short u[16]; int4 v[2]; } ta, tb;
        #pragma unroll
        for (int j = 0; j < 16; ++j) {
            float va = xa[(size_t)j * N_PIX + n0 + nl];
            float vb = xa[(size_t)j * N_PIX + m0 + nl];
            ta.u[j] = f2bf(va * rA);
            tb.u[j] = f2bf(vb * rB);
        }
        __syncthreads();
        *(int4*)&As[((half * 2 + 0) * 128 + nl) * 8] = ta.v[0];
        *(int4*)&As[((half * 2 + 1) * 128 + nl) * 8] = ta.v[1];
        *(int4*)&Bs[((half * 2 + 0) * 128 + nl) * 8] = tb.v[0];
        *(int4*)&Bs[((half * 2 + 1) * 128 + nl) * 8] = tb.v[1];
        __syncthreads();

        bf16x8 af[4], bfr[4];
        #pragma unroll
        for (int mi = 0; mi < 4; ++mi)
            af[mi] = *(const bf16x8*)&As[(quad * 128 + wr * 64 + mi * 16 + lcol) * 8];
        #pragma unroll
        for (int ni = 0; ni < 4; ++ni)
            bfr[ni] = *(const bf16x8*)&Bs[(quad * 128 + wc * 64 + ni * 16 + lcol) * 8];
        #pragma unroll
        for (int mi = 0; mi < 4; ++mi)
            #pragma unroll
            for (int ni = 0; ni < 4; ++ni)
                acc[mi][ni] = __builtin_amdgcn_mfma_f32_16x16x32_bf16(af[mi], bfr[ni], acc[mi][ni], 0, 0, 0);
    }

    float attv[4];
    #pragma unroll
    for (int ni = 0; ni < 4; ++ni)
        attv[ni] = ab[m0 + wc * 64 + ni * 16 + lcol];

    #pragma unroll
    for (int mi = 0; mi < 4; ++mi) {
        float part[4] = {0.f, 0.f, 0.f, 0.f};
        #pragma unroll
        for (int ni = 0; ni < 4; ++ni) {
            #pragma unroll
            for (int r = 0; r < 4; ++r) {
                float s = fmaxf(acc[mi][ni][r], 0.f);
                part[r] = fmaf(s * s, attv[ni], part[r]);
            }
        }
        #pragma unroll
        for (int r = 0; r < 4; ++r) {
            float v = part[r];
            v += __shfl_xor(v, 1);
            v += __shfl_xor(v, 2);
            v += __shfl_xor(v, 4);
            v += __shfl_xor(v, 8);
            if (lcol == 0)
                atomicAdd(&refine[b * N_PIX + n0 + wr * 64 + mi * 16 + quad * 4 + r], v);
        }
    }
}

__global__ __launch_bounds__(256) void pool_fallback(const float* __restrict__ x,
                                                     const float* __restrict__ refine,
                                                     float* __restrict__ out) {
    const int lane = threadIdx.x & 63;
    const int wave = threadIdx.x >> 6;
    const int gidx = blockIdx.x * 4 + wave;
    const int b = gidx >> 9;
    const float4* xr = (const float4*)(x + (size_t)gidx * N_PIX);
    const float4* rr = (const float4*)(refine + (size_t)b * N_PIX);
    float s = 0.f;
    #pragma unroll
    for (int j = 0; j < 9; ++j) {
        float4 xv = xr[j * 64 + lane];
        float4 rv = rr[j * 64 + lane];
        s += xv.x * rv.x + xv.y * rv.y + xv.z * rv.z + xv.w * rv.w;
    }
    #pragma unroll
    for (int off = 32; off > 0; off >>= 1) s += __shfl_down(s, off);
    if (lane == 0) out[gidx] = s * (1.0f / N_PIX);
}

extern "C" void kernel_launch(void* const* d_in, const int* in_sizes, int n_in,
                              void* d_out, int out_size, void* d_ws, size_t ws_size,
                              hipStream_t stream) {
    const float* x = (const float*)d_in[0];
    const float* w = (const float*)d_in[1];
    float* out    = (float*)d_out;

    // fast-path workspace layout (R6-bench proven)
    float* rn2    = (float*)d_ws;
    float* g      = rn2 + NB;
    float* refine = g + NB;
    float* accd   = refine + NB;
    float* accs   = accd + NB;
    unsigned short* F = (unsigned short*)(accs + NB);

    const size_t need = (size_t)5 * NB * 4 + (size_t)B_DIM * FB_STRIDE * 2;

    if (ws_size >= need) {
        hipMemsetAsync(accd, 0, (size_t)2 * NB * 4, stream);   // accd + accs
        xcvt_kernel<<<dim3(144, 16), 256, 0, stream>>>(x, w, F, accd, accs);
        finalize_kernel<<<dim3(NB / 256), 256, 0, stream>>>(accd, accs, g, rn2, refine);
        refine_kernel<<<dim3(171 * 16), 256, 0, stream>>>(F, g, refine);
        pool_kernel<<<dim3(B_DIM * K8), 256, 0, stream>>>(F, refine, rn2, out);
    } else {
        float* rnorm = (float*)d_ws;
        float* att   = rnorm + NB;
        float* refF  = att + NB;
        hipMemsetAsync(refF, 0, (size_t)NB * 4, stream);
        prep_kernel<<<dim3(NB / 64), 256, 0, stream>>>(x, w, rnorm, att);
        refine_fallback<<<dim3(18, 18, B_DIM), 256, 0, stream>>>(x, rnorm, att, refF);
        pool_fallback<<<dim3(B_DIM * C_DIM / 4), 256, 0, stream>>>(x, refF, out);
    }
}

// Round 11
// 183.671 us; speedup vs baseline: 1.0838x; 1.0838x over previous
//
#include <hip/hip_runtime.h>

#define C_DIM 512
#define N_PIX 2304   // 48*48
#define B_DIM 16
#define K8    (C_DIM / 8)          // 64 groups of 8 k
#define K8_STRIDE (N_PIX * 8)      // ushorts per k8 row  (18432)
#define FB_STRIDE ((size_t)K8 * K8_STRIDE)  // ushorts per batch (1179648)
#define NB (B_DIM * N_PIX)         // 36864 pixels total

typedef float floatx4 __attribute__((ext_vector_type(4)));
typedef __bf16 bf16x8 __attribute__((ext_vector_type(8)));

// fp32 -> bf16 round-to-nearest-even
static __device__ __forceinline__ unsigned short f2bf(float f) {
    unsigned u = __float_as_uint(f);
    return (unsigned short)((u + 0x7fffu + ((u >> 16) & 1u)) >> 16);
}

static __device__ __forceinline__ float softplus_stable(float z) {
    return (z > 0.f) ? (z + log1pf(expf(-z))) : log1pf(expf(z));
}

// async global->LDS, 16 B per lane; LDS dest = wave-uniform base + lane*16
static __device__ __forceinline__ void load_lds16(const void* gp, void* l) {
    __builtin_amdgcn_global_load_lds(
        (const __attribute__((address_space(1))) unsigned int*)gp,
        (__attribute__((address_space(3))) unsigned int*)l, 16, 0, 0);
}

// ---------------------------------------------------------------------------
// Kernel 1 (xcvt): single pass over x (R6-bench proven form).
// Grid (144, 16): block = 256 pixels x 32 channels (4 k8 groups).
//   - F[b][k/8][n][k%8] = bf16(raw x)
//   - accd[b,n] += partial dot(w,x); accs[b,n] += partial sum x^2 (atomics)
// ---------------------------------------------------------------------------
__global__ __launch_bounds__(256) void xcvt_kernel(const float* __restrict__ x,
                                                   const float* __restrict__ w,
                                                   unsigned short* __restrict__ F,
                                                   float* __restrict__ accd,
                                                   float* __restrict__ accs) {
    const int pg = blockIdx.x;                 // 0..143 pixel group
    const int cg = blockIdx.y;                 // 0..15 channel group
    const int b  = pg / 9;
    const int p  = (pg - b * 9) * 256 + threadIdx.x;   // pixel within batch
    const float* xb = x + (size_t)b * C_DIM * N_PIX + p;

    float dot = 0.f, sq = 0.f;
    #pragma unroll
    for (int k8l = 0; k8l < 4; ++k8l) {
        const int k8 = cg * 4 + k8l;
        float v[8];
        #pragma unroll
        for (int kk = 0; kk < 8; ++kk)
            v[kk] = xb[(size_t)(k8 * 8 + kk) * N_PIX];
        union { unsigned short u[8]; int4 q; } cell;
        #pragma unroll
        for (int kk = 0; kk < 8; ++kk) {
            dot = fmaf(v[kk], w[k8 * 8 + kk], dot);
            sq  = fmaf(v[kk], v[kk], sq);
            cell.u[kk] = f2bf(v[kk]);
        }
        *(int4*)(F + (size_t)b * FB_STRIDE + (size_t)k8 * K8_STRIDE + (size_t)p * 8) = cell.q;
    }
    atomicAdd(&accd[b * N_PIX + p], dot);
    atomicAdd(&accs[b * N_PIX + p], sq);
}

// ---------------------------------------------------------------------------
// Kernel 1b (finalize): g = softplus(dot)*rn2, rn2 = 1/max(sq,eps), refine=0.
// ---------------------------------------------------------------------------
__global__ __launch_bounds__(256) void finalize_kernel(const float* __restrict__ accd,
                                                       const float* __restrict__ accs,
                                                       float* __restrict__ g,
                                                       float* __restrict__ rn2,
                                                       float* __restrict__ refine) {
    const int bp = blockIdx.x * 256 + threadIdx.x;
    const float d = accd[bp];
    const float s = accs[bp];
    const float r2 = 1.0f / fmaxf(s, 1e-24f);
    g[bp]      = softplus_stable(d) * r2;
    rn2[bp]    = r2;
    refine[bp] = 0.f;
}

// ---------------------------------------------------------------------------
// Kernel 2: symmetric-triangle refine on RAW sim, XCD-partitioned.
// R3/R6-proven staging (best of 6 structural variants tried, R3..R10):
// BK=32, 16 KB LDS, wave w stages kb=w (4 x global_load_lds), 2 barriers.
// __launch_bounds__(256,3): only change vs R6 — request 3 waves/SIMD
// (144 regs = 80V+64A fits 170) so a 3rd resident block overlaps the
// barrier drain. R8 showed VGPR 72 / higher occupancy with this bound.
// ---------------------------------------------------------------------------
__global__ __launch_bounds__(256, 3) void refine_kernel(const unsigned short* __restrict__ F,
                                                        const float* __restrict__ g,
                                                        float* __restrict__ refine) {
    // decode: XCD-partitioned (id%8 ~ XCD), then triangular tile
    const int id   = blockIdx.x;
    const int xcd  = id & 7;
    const int slot = id >> 3;                  // 0..341
    const int hi   = (slot >= 171) ? 1 : 0;
    const int b    = xcd + 8 * hi;
    int t = slot - 171 * hi, bi = 0;
    while (t >= 18 - bi) { t -= 18 - bi; ++bi; }
    const int bj = bi + t;
    const int n0 = bi * 128;          // rows
    const int m0 = bj * 128;          // cols
    const bool mirror = (bi != bj);

    const unsigned short* Fb = F + (size_t)b * FB_STRIDE;
    const float* gb = g + b * N_PIX;

    __shared__ __align__(16) unsigned short As[4 * 128 * 8];  // [kb][row][8]
    __shared__ __align__(16) unsigned short Bs[4 * 128 * 8];

    const int tid  = threadIdx.x;
    const int lane = tid & 63;
    const int wave = tid >> 6;
    const int wr = wave >> 1, wc = wave & 1;
    const int quad = lane >> 4, lcol = lane & 15;

    floatx4 acc[4][4];
    #pragma unroll
    for (int i = 0; i < 4; ++i)
        #pragma unroll
        for (int j = 0; j < 4; ++j)
            acc[i][j] = (floatx4)0.f;

    // wave w stages k-subchunk kb=w for both A and B strips
    const unsigned short* gA = Fb + (size_t)wave * K8_STRIDE + (size_t)n0 * 8 + lane * 8;
    const unsigned short* gB = Fb + (size_t)wave * K8_STRIDE + (size_t)m0 * 8 + lane * 8;

    for (int ck = 0; ck < 16; ++ck) {
        const unsigned short* sA = gA + (size_t)ck * (4 * K8_STRIDE);
        const unsigned short* sB = gB + (size_t)ck * (4 * K8_STRIDE);
        __syncthreads();   // previous chunk's ds_reads complete
        load_lds16(sA,       &As[wave * 1024]);
        load_lds16(sA + 512, &As[wave * 1024 + 512]);
        load_lds16(sB,       &Bs[wave * 1024]);
        load_lds16(sB + 512, &Bs[wave * 1024 + 512]);
        __syncthreads();   // drains vmcnt -> LDS populated

        bf16x8 af[4], bfr[4];
        #pragma unroll
        for (int mi = 0; mi < 4; ++mi)
            af[mi] = *(const bf16x8*)&As[(quad * 128 + wr * 64 + mi * 16 + lcol) * 8];
        #pragma unroll
        for (int ni = 0; ni < 4; ++ni)
            bfr[ni] = *(const bf16x8*)&Bs[(quad * 128 + wc * 64 + ni * 16 + lcol) * 8];
        #pragma unroll
        for (int mi = 0; mi < 4; ++mi)
            #pragma unroll
            for (int ni = 0; ni < 4; ++ni)
                acc[mi][ni] = __builtin_amdgcn_mfma_f32_16x16x32_bf16(af[mi], bfr[ni], acc[mi][ni], 0, 0, 0);
    }

    // ---- standard contribution: reduce over cols -> refine_raw[rows]
    float gC[4];
    #pragma unroll
    for (int ni = 0; ni < 4; ++ni)
        gC[ni] = gb[m0 + wc * 64 + ni * 16 + lcol];

    #pragma unroll
    for (int mi = 0; mi < 4; ++mi) {
        float part[4] = {0.f, 0.f, 0.f, 0.f};
        #pragma unroll
        for (int ni = 0; ni < 4; ++ni) {
            #pragma unroll
            for (int r = 0; r < 4; ++r) {
                float s = fmaxf(acc[mi][ni][r], 0.f);
                part[r] = fmaf(s * s, gC[ni], part[r]);
            }
        }
        #pragma unroll
        for (int r = 0; r < 4; ++r) {
            float v = part[r];
            v += __shfl_xor(v, 1);
            v += __shfl_xor(v, 2);
            v += __shfl_xor(v, 4);
            v += __shfl_xor(v, 8);
            if (lcol == 0)
                atomicAdd(&refine[b * N_PIX + n0 + wr * 64 + mi * 16 + quad * 4 + r], v);
        }
    }

    // ---- mirror contribution: reduce over rows -> refine_raw[cols]
    if (mirror) {
        float gR[4][4];
        #pragma unroll
        for (int mi = 0; mi < 4; ++mi)
            #pragma unroll
            for (int r = 0; r < 4; ++r)
                gR[mi][r] = gb[n0 + wr * 64 + mi * 16 + quad * 4 + r];

        #pragma unroll
        for (int ni = 0; ni < 4; ++ni) {
            float msum = 0.f;
            #pragma unroll
            for (int mi = 0; mi < 4; ++mi) {
                #pragma unroll
                for (int r = 0; r < 4; ++r) {
                    float s = fmaxf(acc[mi][ni][r], 0.f);
                    msum = fmaf(s * s, gR[mi][r], msum);
                }
            }
            msum += __shfl_xor(msum, 16);
            msum += __shfl_xor(msum, 32);
            if (quad == 0)
                atomicAdd(&refine[b * N_PIX + m0 + wc * 64 + ni * 16 + lcol], msum);
        }
    }
}

// ---------------------------------------------------------------------------
// Kernel 3 (pool): out[b,c] = mean_n F[b,c,n] * refine_raw[n] * rn2[n]
// One block per (b,k8): grid 1024, 4 waves split the 36 n-strips.
// ---------------------------------------------------------------------------
__global__ __launch_bounds__(256) void pool_kernel(const unsigned short* __restrict__ F,
                                                   const float* __restrict__ refine,
                                                   const float* __restrict__ rn2,
                                                   float* __restrict__ out) {
    const int lane = threadIdx.x & 63;
    const int wave = threadIdx.x >> 6;
    const int b  = blockIdx.x >> 6;
    const int k8 = blockIdx.x & 63;
    const unsigned short* Fr = F + (size_t)b * FB_STRIDE + (size_t)k8 * K8_STRIDE;
    const float* rf = refine + b * N_PIX;
    const float* r2 = rn2 + b * N_PIX;
    float s[8] = {0.f, 0.f, 0.f, 0.f, 0.f, 0.f, 0.f, 0.f};
    #pragma unroll
    for (int j = 0; j < 9; ++j) {             // (j*4+wave) in 0..35
        const int n = (j * 4 + wave) * 64 + lane;
        bf16x8 fv = *(const bf16x8*)(Fr + (size_t)n * 8);
        float rr = rf[n] * r2[n];
        #pragma unroll
        for (int kk = 0; kk < 8; ++kk)
            s[kk] = fmaf((float)fv[kk], rr, s[kk]);
    }
    __shared__ float sred[4][8];
    #pragma unroll
    for (int kk = 0; kk < 8; ++kk) {
        float v = s[kk];
        #pragma unroll
        for (int off = 32; off > 0; off >>= 1) v += __shfl_down(v, off);
        if (lane == 0) sred[wave][kk] = v;
    }
    __syncthreads();
    if (threadIdx.x < 8) {
        const int kk = threadIdx.x;
        out[b * C_DIM + k8 * 8 + kk] =
            (sred[0][kk] + sred[1][kk] + sred[2][kk] + sred[3][kk]) * (1.0f / N_PIX);
    }
}

// ---------------------------------------------------------------------------
// Fallback path (ws too small): R1-style, no F materialization.
// ---------------------------------------------------------------------------
__global__ __launch_bounds__(256) void prep_kernel(const float* __restrict__ x,
                                                   const float* __restrict__ w,
                                                   float* __restrict__ rnorm,
                                                   float* __restrict__ att) {
    const int tid = threadIdx.x;
    const int px = tid & 63;
    const int cc = tid >> 6;
    const int pglob = blockIdx.x * 64 + px;
    const int b = pglob / N_PIX;
    const int p = pglob - b * N_PIX;

    const float* xb = x + (size_t)b * C_DIM * N_PIX + p;
    float dot = 0.f, sq = 0.f;
    #pragma unroll 4
    for (int c = cc * 128; c < cc * 128 + 128; ++c) {
        float v = xb[(size_t)c * N_PIX];
        dot = fmaf(v, w[c], dot);
        sq  = fmaf(v, v, sq);
    }
    __shared__ float sdot[4][64];
    __shared__ float ssq[4][64];
    sdot[cc][px] = dot;
    ssq[cc][px]  = sq;
    __syncthreads();
    if (cc == 0) {
        dot = sdot[0][px] + sdot[1][px] + sdot[2][px] + sdot[3][px];
        sq  = ssq[0][px]  + ssq[1][px]  + ssq[2][px]  + ssq[3][px];
        att[pglob] = softplus_stable(dot);
        rnorm[pglob] = 1.0f / fmaxf(sqrtf(sq), 1e-12f);
    }
}

__global__ __launch_bounds__(256) void refine_fallback(const float* __restrict__ x,
                                                       const float* __restrict__ rnorm,
                                                       const float* __restrict__ att,
                                                       float* __restrict__ refine) {
    const int b  = blockIdx.z;
    const int n0 = blockIdx.x * 128;
    const int m0 = blockIdx.y * 128;
    const float* xb = x + (size_t)b * C_DIM * N_PIX;
    const float* rn = rnorm + b * N_PIX;
    const float* ab = att + b * N_PIX;

    __shared__ __align__(16) unsigned short As[4 * 128 * 8];
    __shared__ __align__(16) unsigned short Bs[4 * 128 * 8];

    const int tid  = threadIdx.x;
    const int nl   = tid & 127;
    const int half = tid >> 7;
    const int lane = tid & 63;
    const int wave = tid >> 6;
    const int wr = wave >> 1, wc = wave & 1;
    const int quad = lane >> 4, lcol = lane & 15;

    const float rA = rn[n0 + nl];
    const float rB = rn[m0 + nl];

    floatx4 acc[4][4];
    #pragma unroll
    for (int i = 0; i < 4; ++i)
        #pragma unroll
        for (int j = 0; j < 4; ++j)
            acc[i][j] = (floatx4)0.f;

    for (int k0 = 0; k0 < C_DIM; k0 += 32) {
        const float* xa = xb + (size_t)(k0 + half * 16) * N_PIX;
        union { unsigned short u[16]; int4 v[2]; } ta, tb;
        #pragma unroll
        for (int j = 0; j < 16; ++j) {
            float va = xa[(size_t)j * N_PIX + n0 + nl];
            float vb = xa[(size_t)j * N_PIX + m0 + nl];
            ta.u[j] = f2bf(va * rA);
            tb.u[j] = f2bf(vb * rB);
        }
        __syncthreads();
        *(int4*)&As[((half * 2 + 0) * 128 + nl) * 8] = ta.v[0];
        *(int4*)&As[((half * 2 + 1) * 128 + nl) * 8] = ta.v[1];
        *(int4*)&Bs[((half * 2 + 0) * 128 + nl) * 8] = tb.v[0];
        *(int4*)&Bs[((half * 2 + 1) * 128 + nl) * 8] = tb.v[1];
        __syncthreads();

        bf16x8 af[4], bfr[4];
        #pragma unroll
        for (int mi = 0; mi < 4; ++mi)
            af[mi] = *(const bf16x8*)&As[(quad * 128 + wr * 64 + mi * 16 + lcol) * 8];
        #pragma unroll
        for (int ni = 0; ni < 4; ++ni)
            bfr[ni] = *(const bf16x8*)&Bs[(quad * 128 + wc * 64 + ni * 16 + lcol) * 8];
        #pragma unroll
        for (int mi = 0; mi < 4; ++mi)
            #pragma unroll
            for (int ni = 0; ni < 4; ++ni)
                acc[mi][ni] = __builtin_amdgcn_mfma_f32_16x16x32_bf16(af[mi], bfr[ni], acc[mi][ni], 0, 0, 0);
    }

    float attv[4];
    #pragma unroll
    for (int ni = 0; ni < 4; ++ni)
        attv[ni] = ab[m0 + wc * 64 + ni * 16 + lcol];

    #pragma unroll
    for (int mi = 0; mi < 4; ++mi) {
        float part[4] = {0.f, 0.f, 0.f, 0.f};
        #pragma unroll
        for (int ni = 0; ni < 4; ++ni) {
            #pragma unroll
            for (int r = 0; r < 4; ++r) {
                float s = fmaxf(acc[mi][ni][r], 0.f);
                part[r] = fmaf(s * s, attv[ni], part[r]);
            }
        }
        #pragma unroll
        for (int r = 0; r < 4; ++r) {
            float v = part[r];
            v += __shfl_xor(v, 1);
            v += __shfl_xor(v, 2);
            v += __shfl_xor(v, 4);
            v += __shfl_xor(v, 8);
            if (lcol == 0)
                atomicAdd(&refine[b * N_PIX + n0 + wr * 64 + mi * 16 + quad * 4 + r], v);
        }
    }
}

__global__ __launch_bounds__(256) void pool_fallback(const float* __restrict__ x,
                                                     const float* __restrict__ refine,
                                                     float* __restrict__ out) {
    const int lane = threadIdx.x & 63;
    const int wave = threadIdx.x >> 6;
    const int gidx = blockIdx.x * 4 + wave;
    const int b = gidx >> 9;
    const float4* xr = (const float4*)(x + (size_t)gidx * N_PIX);
    const float4* rr = (const float4*)(refine + (size_t)b * N_PIX);
    float s = 0.f;
    #pragma unroll
    for (int j = 0; j < 9; ++j) {
        float4 xv = xr[j * 64 + lane];
        float4 rv = rr[j * 64 + lane];
        s += xv.x * rv.x + xv.y * rv.y + xv.z * rv.z + xv.w * rv.w;
    }
    #pragma unroll
    for (int off = 32; off > 0; off >>= 1) s += __shfl_down(s, off);
    if (lane == 0) out[gidx] = s * (1.0f / N_PIX);
}

extern "C" void kernel_launch(void* const* d_in, const int* in_sizes, int n_in,
                              void* d_out, int out_size, void* d_ws, size_t ws_size,
                              hipStream_t stream) {
    const float* x = (const float*)d_in[0];
    const float* w = (const float*)d_in[1];
    float* out    = (float*)d_out;

    // fast-path workspace layout (R6-bench proven)
    float* rn2    = (float*)d_ws;
    float* g      = rn2 + NB;
    float* refine = g + NB;
    float* accd   = refine + NB;
    float* accs   = accd + NB;
    unsigned short* F = (unsigned short*)(accs + NB);

    const size_t need = (size_t)5 * NB * 4 + (size_t)B_DIM * FB_STRIDE * 2;

    if (ws_size >= need) {
        hipMemsetAsync(accd, 0, (size_t)2 * NB * 4, stream);   // accd + accs
        xcvt_kernel<<<dim3(144, 16), 256, 0, stream>>>(x, w, F, accd, accs);
        finalize_kernel<<<dim3(NB / 256), 256, 0, stream>>>(accd, accs, g, rn2, refine);
        refine_kernel<<<dim3(171 * 16), 256, 0, stream>>>(F, g, refine);
        pool_kernel<<<dim3(B_DIM * K8), 256, 0, stream>>>(F, refine, rn2, out);
    } else {
        float* rnorm = (float*)d_ws;
        float* att   = rnorm + NB;
        float* refF  = att + NB;
        hipMemsetAsync(refF, 0, (size_t)NB * 4, stream);
        prep_kernel<<<dim3(NB / 64), 256, 0, stream>>>(x, w, rnorm, att);
        refine_fallback<<<dim3(18, 18, B_DIM), 256, 0, stream>>>(x, rnorm, att, refF);
        pool_fallback<<<dim3(B_DIM * C_DIM / 4), 256, 0, stream>>>(x, refF, out);
    }
}